// Round 3
// baseline (404.405 us; speedup 1.0000x reference)
//
#include <hip/hip_runtime.h>

// Problem constants
#define Bn   16
#define Fn   48
#define Hn   256
#define Wn   256
#define Mn   51

#define TH   32
#define TW   32

// s_in: fp32, 47 rows x 54 cols used, stride 56
#define SIN_S 56
// out accumulator stride
#define S3    33

// Workspace layout (floats)
#define WS_SUMSQ 0
#define WS_WN    16
#define WS_TAB   2368               // 48*3200 float2 = 307200 floats
#define WS_FRG   309568             // 14 tiles * 64 lanes * uint4 = 3584 floats

typedef short short8 __attribute__((ext_vector_type(8)));
typedef float f32x4 __attribute__((ext_vector_type(4)));

__device__ __forceinline__ float waveReduceSum(float v) {
    #pragma unroll
    for (int o = 32; o > 0; o >>= 1) v += __shfl_xor(v, o);
    return v;
}

__device__ __host__ __forceinline__ unsigned short f2bf(float x) {
    unsigned int u = __builtin_bit_cast(unsigned int, x);
    unsigned int r = (u + 0x7FFFu + ((u >> 16) & 1u)) >> 16;
    return (unsigned short)r;
}

// ---- weight normalize ----
__global__ __launch_bounds__(64) void prep_kernel(const float* __restrict__ cw,
                                                  const float* __restrict__ scale_f,
                                                  float* __restrict__ ws) {
    int f = blockIdx.x;
    int t = threadIdx.x;
    float v = (t < 49) ? cw[f * 49 + t] : 0.0f;
    float mean = waveReduceSum(v) * (1.0f / 49.0f);
    float c = (t < 49) ? (v - mean) : 0.0f;
    float nrm = sqrtf(waveReduceSum(c * c));
    float o = scale_f[f] * c / (nrm + 1e-12f);
    if (t < 49) ws[WS_WN + f * 49 + t] = o;
    if (f == 0 && t < 16) ws[WS_SUMSQ + t] = 0.0f;
}

// ---- RBF pair-LUT ----
__global__ __launch_bounds__(256) void tab_kernel(const float* __restrict__ rw,
                                                  const float* __restrict__ rc,
                                                  float* __restrict__ ws) {
    int f = blockIdx.y;
    int idx = blockIdx.x * 256 + threadIdx.x;
    if (idx >= 3200) return;
    float x0 = -100.0f + 0.0625f * (float)idx;
    float x1 = x0 + 0.0625f;
    float v0 = 0.f, v1 = 0.f;
    for (int m = 0; m < Mn; ++m) {
        float c = rc[m];
        float wm = rw[f * Mn + m];
        float d0 = x0 - c, d1 = x1 - c;
        v0 += wm * __expf(-0.01f * d0 * d0);
        v1 += wm * __expf(-0.01f * d1 * d1);
    }
    float2* tab2 = (float2*)(ws + WS_TAB);
    tab2[f * 3200 + idx] = make_float2(v0, v1);
}

// ---- prebuilt MFMA weight fragments (bf16) ----
// z-GEMM A: A[m=filter][k=tap]; tiles (mt 0..2, kt 0..1) -> slot mt*2+kt
// c-GEMM A2: A2[m=tap][k=filter]; tiles (mt 0..3, kt 0..1) -> slot 6+mt*2+kt
__global__ __launch_bounds__(64) void wfrag_kernel(float* __restrict__ ws) {
    int lane = threadIdx.x;
    int quad = lane >> 4, l15 = lane & 15;
    const float* wn = ws + WS_WN;
    uint4* frg = (uint4*)(ws + WS_FRG);
    for (int mt = 0; mt < 3; ++mt)
        for (int kt = 0; kt < 2; ++kt) {
            unsigned int pk[4] = {0, 0, 0, 0};
            int f = mt * 16 + l15;
            for (int j = 0; j < 8; ++j) {
                int tap = kt * 32 + quad * 8 + j;
                float v = (tap < 49) ? wn[f * 49 + tap] : 0.f;
                pk[j >> 1] |= (unsigned int)f2bf(v) << (16 * (j & 1));
            }
            frg[(mt * 2 + kt) * 64 + lane] = make_uint4(pk[0], pk[1], pk[2], pk[3]);
        }
    for (int mt = 0; mt < 4; ++mt)
        for (int kt = 0; kt < 2; ++kt) {
            unsigned int pk[4] = {0, 0, 0, 0};
            int tap = mt * 16 + l15;
            int p = tap / 7, q = tap - p * 7;
            for (int j = 0; j < 8; ++j) {
                int f = kt * 32 + quad * 8 + j;
                float v = (tap < 49 && f < 48) ? wn[f * 49 + (6 - p) * 7 + (6 - q)] : 0.f;
                pk[j >> 1] |= (unsigned int)f2bf(v) << (16 * (j & 1));
            }
            frg[(6 + mt * 2 + kt) * 64 + lane] = make_uint4(pk[0], pk[1], pk[2], pk[3]);
        }
}

// ---- fused MFMA kernel ----
__global__ __launch_bounds__(256) void fused_kernel(const float* __restrict__ input,
                                                    const float* __restrict__ net,
                                                    float* __restrict__ ws,
                                                    float* __restrict__ rout) {
    __shared__ __align__(16) float s_in[47 * SIN_S];
    __shared__ __align__(16) unsigned short s_a[4][48 * 64];  // per-wave a-row [ax][f], XOR-swizzled
    __shared__ __align__(16) float s_out[32 * S3];
    __shared__ float s_red[4];

    const int tid = threadIdx.x;
    const int lane = tid & 63;
    const int wv = tid >> 6;
    const int quad = lane >> 4;
    const int l15 = lane & 15;
    const int bz = blockIdx.z;
    const int ty0 = blockIdx.y * TH;
    const int tx0 = blockIdx.x * TW;
    const float* img = input + bz * (Hn * Wn);

    // stage s_in: rows 0..43 data (sym pad), 44..46 zero; cols 0..53
    for (int k = tid; k < 47 * 54; k += 256) {
        int j = k / 54, i = k % 54;
        float v = 0.f;
        if (j < 44) {
            int gy = ty0 - 6 + j;
            int gx = tx0 - 6 + i;
            gy = (gy < 0) ? (-1 - gy) : ((gy > 255) ? (511 - gy) : gy);
            gx = (gx < 0) ? (-1 - gx) : ((gx > 255) ? (511 - gx) : gx);
            v = img[gy * Wn + gx];
        }
        s_in[j * SIN_S + i] = v;
    }
    // zero out accumulator
    for (int k = tid; k < 32 * S3; k += 256) s_out[k] = 0.f;
    // zero a_s filter-pad blocks (f = 48..63, blk 6..7) for every wave plane
    for (int k = tid; k < 4 * 48 * 2; k += 256) {
        int w = k / 96, rem = k % 96;
        int ax = rem >> 1, bb = 6 + (rem & 1);
        unsigned int off = (unsigned int)(ax * 64 + ((bb ^ (ax & 7)) * 8));
        *(uint4*)&s_a[w][off] = make_uint4(0, 0, 0, 0);
    }
    __syncthreads();

    // load constant weight fragments
    const uint4* frg = (const uint4*)(ws + WS_FRG);
    short8 Afz[3][2], Afc[4][2];
    #pragma unroll
    for (int mt = 0; mt < 3; ++mt)
        #pragma unroll
        for (int kt = 0; kt < 2; ++kt)
            Afz[mt][kt] = __builtin_bit_cast(short8, frg[(mt * 2 + kt) * 64 + lane]);
    #pragma unroll
    for (int mt = 0; mt < 4; ++mt)
        #pragma unroll
        for (int kt = 0; kt < 2; ++kt)
            Afc[mt][kt] = __builtin_bit_cast(short8, frg[(6 + mt * 2 + kt) * 64 + lane]);

    // per-lane im2col offsets for z B-frags
    int offB[2][8];
    #pragma unroll
    for (int kt = 0; kt < 2; ++kt)
        #pragma unroll
        for (int j = 0; j < 8; ++j) {
            int k = kt * 32 + quad * 8 + j;
            int ky = k / 7; if (ky > 6) ky = 6;
            int kx = k % 7;
            offB[kt][j] = ky * SIN_S + kx + l15;
        }
    // per-lane scatter constants: e = mt*4+r, tap = mt*16 + quad*4 + r
    int offD[16], pm[16];
    #pragma unroll
    for (int mt = 0; mt < 4; ++mt)
        #pragma unroll
        for (int r = 0; r < 4; ++r) {
            int e = mt * 4 + r;
            int tap = mt * 16 + quad * 4 + r;
            int p = tap / 7, q = tap - p * 7;
            offD[e] = -(p * S3) - q;
            int m3 = 0;
            if (tap < 49) {
                #pragma unroll
                for (int nt = 0; nt < 3; ++nt) {
                    int c = l15 + nt * 16 - q;
                    if (c >= 0 && c < 32) m3 |= 1 << nt;
                }
            }
            pm[e] = (p & 15) | (m3 << 4);
        }

    const float2* tab2 = (const float2*)(ws + WS_TAB);

    for (int ay = wv; ay < 38; ay += 4) {
        const int gy = ty0 - 3 + ay;
        if ((unsigned)gy >= (unsigned)Hn) continue;
        const int ayS = ay * SIN_S;

        // ---- stage 1: z GEMM + lerp -> a row ----
        #pragma unroll
        for (int nt = 0; nt < 3; ++nt) {
            short8 Bf[2];
            #pragma unroll
            for (int kt = 0; kt < 2; ++kt) {
                short8 b;
                #pragma unroll
                for (int j = 0; j < 8; ++j) {
                    float v = s_in[ayS + offB[kt][j] + nt * 16];
                    b[j] = (short)f2bf(v);
                }
                Bf[kt] = b;
            }
            f32x4 zacc[3];
            #pragma unroll
            for (int mt = 0; mt < 3; ++mt) {
                f32x4 z0 = {0.f, 0.f, 0.f, 0.f};
                z0 = __builtin_amdgcn_mfma_f32_16x16x32_bf16(Afz[mt][0], Bf[0], z0, 0, 0, 0);
                z0 = __builtin_amdgcn_mfma_f32_16x16x32_bf16(Afz[mt][1], Bf[1], z0, 0, 0, 0);
                zacc[mt] = z0;
            }
            const int ax = l15 + nt * 16;
            const int gx = tx0 - 3 + ax;
            const bool cv = ((unsigned)gx < (unsigned)Wn);
            #pragma unroll
            for (int mt = 0; mt < 3; ++mt) {
                unsigned int pk[2] = {0, 0};
                #pragma unroll
                for (int r = 0; r < 4; ++r) {
                    int f = mt * 16 + quad * 4 + r;
                    float z = zacc[mt][r];
                    float xc = fminf(fmaxf(z, -100.f), 100.f);
                    float tt = (xc + 100.f) * 16.0f;
                    int i = (int)tt;
                    i = (i > 3199) ? 3199 : i;
                    float fr = tt - (float)i;
                    float2 pch = tab2[f * 3200 + i];
                    float a = fmaf(fr, pch.y - pch.x, pch.x);
                    a = cv ? a : 0.f;
                    pk[r >> 1] |= (unsigned int)f2bf(a) << (16 * (r & 1));
                }
                int blkp = (2 * mt + (quad >> 1)) ^ (ax & 7);
                unsigned int off = (unsigned int)(ax * 64 + blkp * 8 + (quad & 1) * 4);
                *(uint2*)&s_a[wv][off] = make_uint2(pk[0], pk[1]);
            }
        }

        // ---- stage 2: convT GEMM + scatter-add ----
        const int base0 = ay * S3;
        #pragma unroll
        for (int nt = 0; nt < 3; ++nt) {
            const int ax = l15 + nt * 16;
            short8 B2[2];
            #pragma unroll
            for (int kt = 0; kt < 2; ++kt)
                B2[kt] = *(const short8*)&s_a[wv][ax * 64 + ((4 * kt + quad) ^ (ax & 7)) * 8];
            f32x4 d2[4];
            #pragma unroll
            for (int mt = 0; mt < 4; ++mt) {
                f32x4 c0 = {0.f, 0.f, 0.f, 0.f};
                c0 = __builtin_amdgcn_mfma_f32_16x16x32_bf16(Afc[mt][0], B2[0], c0, 0, 0, 0);
                c0 = __builtin_amdgcn_mfma_f32_16x16x32_bf16(Afc[mt][1], B2[1], c0, 0, 0, 0);
                d2[mt] = c0;
            }
            const int base = base0 + ax;
            #pragma unroll
            for (int mt = 0; mt < 4; ++mt)
                #pragma unroll
                for (int r = 0; r < 4; ++r) {
                    int e = mt * 4 + r;
                    int p = pm[e] & 15, m3 = pm[e] >> 4;
                    if (((unsigned)(ay - p) < 32u) && ((m3 >> nt) & 1))
                        atomicAdd(&s_out[base + offD[e]], d2[mt][r]);
                }
        }
    }

    __syncthreads();

    // epilogue: r = input - convt - net
    const float* netb = net + bz * (Hn * Wn);
    float* rb = rout + bz * (Hn * Wn);
    float rsq = 0.f;
    #pragma unroll
    for (int t = 0; t < 4; ++t) {
        const int row = wv * 8 + (lane >> 5) + t * 2;
        const int ox = lane & 31;
        const int gy = ty0 + row, gx = tx0 + ox;
        const float conv = s_out[row * S3 + ox];
        const float iv = s_in[(row + 6) * SIN_S + ox + 6];
        const float r = iv - conv - netb[gy * Wn + gx];
        rb[gy * Wn + gx] = r;
        rsq += r * r;
    }
    rsq = waveReduceSum(rsq);
    if (lane == 0) s_red[wv] = rsq;
    __syncthreads();
    if (tid == 0) atomicAdd(&ws[WS_SUMSQ + bz], s_red[0] + s_red[1] + s_red[2] + s_red[3]);
}

__global__ __launch_bounds__(256) void finalize_kernel(const float* __restrict__ net,
                                                       const float* __restrict__ stdn,
                                                       const float* __restrict__ alpha,
                                                       const float* __restrict__ ws,
                                                       float* __restrict__ out) {
    const int b = blockIdx.y;
    const float sum = ws[WS_SUMSQ + b];
    const float k = __expf(alpha[0]) * stdn[b] * 256.0f;
    const float nr = sqrtf(sum);
    const float scale = fminf(1.0f, k / (nr + 1e-12f));
    const int base = b * (Hn * Wn) + (blockIdx.x * 256 + threadIdx.x) * 4;
    float4 rv = *(const float4*)(out + base);
    const float4 nv = *(const float4*)(net + base);
    float4 o;
    o.x = fmaf(rv.x, scale, nv.x);
    o.y = fmaf(rv.y, scale, nv.y);
    o.z = fmaf(rv.z, scale, nv.z);
    o.w = fmaf(rv.w, scale, nv.w);
    *(float4*)(out + base) = o;
}

extern "C" void kernel_launch(void* const* d_in, const int* in_sizes, int n_in,
                              void* d_out, int out_size, void* d_ws, size_t ws_size,
                              hipStream_t stream) {
    const float* input = (const float*)d_in[0];
    const float* stdn  = (const float*)d_in[1];
    const float* net   = (const float*)d_in[3];
    const float* cw    = (const float*)d_in[4];
    const float* sf    = (const float*)d_in[5];
    const float* alpha = (const float*)d_in[6];
    const float* rw    = (const float*)d_in[7];
    const float* rc    = (const float*)d_in[8];
    float* out = (float*)d_out;
    float* ws  = (float*)d_ws;

    prep_kernel<<<dim3(Fn), 64, 0, stream>>>(cw, sf, ws);
    tab_kernel<<<dim3(13, Fn), 256, 0, stream>>>(rw, rc, ws);
    wfrag_kernel<<<dim3(1), 64, 0, stream>>>(ws);
    fused_kernel<<<dim3(Wn / TW, Hn / TH, Bn), 256, 0, stream>>>(input, net, ws, out);
    finalize_kernel<<<dim3(64, Bn), 256, 0, stream>>>(net, stdn, alpha, ws, out);
}